// Round 3
// baseline (774.481 us; speedup 1.0000x reference)
//
#include <hip/hip_runtime.h>
#include <math.h>

#define NN 8192
#define FIN 128
#define HD 32
#define NC 10
#define NE 262144
#define EPSBN 1e-5f

typedef short short8 __attribute__((ext_vector_type(8)));
typedef float f32x4 __attribute__((ext_vector_type(4)));

__device__ __forceinline__ float bf2f(unsigned short b) {
  unsigned int u = ((unsigned int)b) << 16;
  float f;
  __builtin_memcpy(&f, &u, 4);
  return f;
}
__device__ __forceinline__ unsigned short f2bf(float f) {
  unsigned int u;
  __builtin_memcpy(&u, &f, 4);
  u = u + 0x7fffu + ((u >> 16) & 1u);
  return (unsigned short)(u >> 16);
}
__device__ __forceinline__ short8 ld_bf8(const unsigned short* p) {
  uint4 u = *(const uint4*)p;
  return __builtin_bit_cast(short8, u);
}
__device__ __forceinline__ float ldin(const void* p, int i, int isf) {
  if (isf) return ((const float*)p)[i];
  return bf2f(((const unsigned short*)p)[i]);
}

// ---------- dtype detection: even-indexed shorts of b (f32 low-mantissa halves are random) ----
__global__ void detect_k(const void* __restrict__ b, int* __restrict__ flag) {
  const unsigned short* p = (const unsigned short*)b;
  int t = threadIdx.x;
  unsigned short s = p[2 * t];
  int e = (s >> 7) & 0xFF;
  int hit = (e >= 110 && e <= 135) ? 1 : 0;
  __shared__ int cnt[256];
  cnt[t] = hit;
  __syncthreads();
  for (int o = 128; o > 0; o >>= 1) {
    if (t < o) cnt[t] += cnt[t + o];
    __syncthreads();
  }
  if (t == 0) flag[0] = (cnt[0] < 128) ? 1 : 0;  // 1 = f32 inputs
}

// ---------- T = Wa1@Wa2 ; vv = ba1@Wa2 + ba2 ----------
__global__ void prep_T(const void* __restrict__ Wa1, const void* __restrict__ ba1,
                       const void* __restrict__ Wa2, const void* __restrict__ ba2,
                       const int* __restrict__ flg, float* __restrict__ T, float* __restrict__ vv) {
  int isf = *flg;
  __shared__ float sW1[1024], sW2[1024];
  int t = threadIdx.x;
  sW1[t] = ldin(Wa1, t, isf);
  sW2[t] = ldin(Wa2, t, isf);
  __syncthreads();
  {
    int c = t >> 5, c2 = t & 31;
    float acc = 0.f;
    for (int k = 0; k < 32; k++) acc += sW1[c * 32 + k] * sW2[k * 32 + c2];
    T[c * 32 + c2] = acc;
  }
  if (t < 32) {
    float acc = ldin(ba2, t, isf);
    for (int k = 0; k < 32; k++) acc += ldin(ba1, k, isf) * sW2[k * 32 + t];
    vv[t] = acc;
  }
}

// ---------- M = T@Wa3 packed to MFMA B-frag (bf16); r2 = vv@Wa3 + ba3 ----------
__global__ void compute_Rp(const void* __restrict__ Wa3, const void* __restrict__ ba3,
                           const float* __restrict__ T, const float* __restrict__ vv,
                           const int* __restrict__ flg,
                           float* __restrict__ r2, unsigned short* __restrict__ Rp) {
  int isf = *flg;
  __shared__ float sT[1024], sv[32];
  int t = threadIdx.x;
  for (int i = t; i < 1024; i += 256) sT[i] = T[i];
  if (t < 32) sv[t] = vv[t];
  __syncthreads();
  int j = blockIdx.x * 256 + t;
  float w3[32];
  for (int c = 0; c < 32; c++) w3[c] = ldin(Wa3, c * NN + j, isf);
  float rr = ldin(ba3, j, isf);
  for (int c = 0; c < 32; c++) rr += sv[c] * w3[c];
  r2[j] = rr;
  float Rcol[32];
  for (int c = 0; c < 32; c++) {
    float acc = 0.f;
    for (int cp = 0; cp < 32; cp++) acc += sT[c * 32 + cp] * w3[cp];
    Rcol[c] = acc;
  }
  int jt = j >> 4, n = j & 15;
  for (int q = 0; q < 4; q++)
    for (int jj = 0; jj < 8; jj++)
      Rp[(size_t)(jt * 64 + q * 16 + n) * 8 + jj] = f2bf(Rcol[q * 8 + jj]);
}

// ---------- pack Wa0 [8192,32] into MFMA B-frag layout (bf16) ----------
__global__ void pack_Bp(const void* __restrict__ Wa0, const int* __restrict__ flg,
                        unsigned short* __restrict__ Bp) {
  int isf = *flg;
  int tid = blockIdx.x * 256 + threadIdx.x;  // 0..32767
  int kb = tid >> 7;
  int h = (tid >> 6) & 1;
  int L = tid & 63;
  int q = L >> 4, n = L & 15;
  int base_k = kb * 32 + q * 8;
  if (isf) {
    const float* W = (const float*)Wa0;
    for (int j = 0; j < 8; j++)
      Bp[(size_t)((kb * 2 + h) * 64 + L) * 8 + j] = f2bf(W[(base_k + j) * HD + h * 16 + n]);
  } else {
    const unsigned short* W = (const unsigned short*)Wa0;
    for (int j = 0; j < 8; j++)
      Bp[(size_t)((kb * 2 + h) * 64 + L) * 8 + j] = W[(base_k + j) * HD + h * 16 + n];
  }
}

// ---------- degree count, then in-place dinv ----------
__global__ void deg_k(const int* __restrict__ dst, float* __restrict__ deg) {
  int e = blockIdx.x * 256 + threadIdx.x;
  atomicAdd(&deg[dst[e]], 1.0f);
}
__global__ void dinv_k(float* __restrict__ deg) {
  int i = blockIdx.x * 256 + threadIdx.x;
  deg[i] = rsqrtf(deg[i] + 1.0f);  // +1 self-loop
}

// ---------- h0 = x @ W0 ----------
__global__ void gemm_x_w0(const void* __restrict__ x, const void* __restrict__ W0,
                          const int* __restrict__ flg, float* __restrict__ h0) {
  int isf = *flg;
  __shared__ float sW[FIN * HD];
  __shared__ float sx[8 * FIN];
  int t = threadIdx.x;
  for (int i = t; i < FIN * HD; i += 256) sW[i] = ldin(W0, i, isf);
  int row0 = blockIdx.x * 8;
  for (int i = t; i < 8 * FIN; i += 256) {
    int r = i >> 7, k = i & 127;
    sx[i] = ldin(x, (row0 + r) * FIN + k, isf);
  }
  __syncthreads();
  int r = t >> 5, c = t & 31;
  float acc = 0.f;
  for (int k = 0; k < FIN; k++) acc += sx[r * FIN + k] * sW[k * HD + c];
  h0[(row0 + r) * HD + c] = acc;
}

// ---------- edge scatter: agg[d] += dinv[s]*dinv[d]*h[s] ----------
__global__ void scatter_agg(const int* __restrict__ src, const int* __restrict__ dst,
                            const float* __restrict__ dinv, const float* __restrict__ h,
                            float* __restrict__ agg) {
  int tid = blockIdx.x * 256 + threadIdx.x;
  int idx = tid >> 5, c = tid & 31;
  int s, d;
  if (idx < NE) { s = src[idx]; d = dst[idx]; }
  else { s = d = idx - NE; }
  float wgt = dinv[s] * dinv[d];
  atomicAdd(&agg[d * HD + c], wgt * h[s * HD + c]);
}

// ---------- BN column stats ----------
__global__ void bn_stats(const float* __restrict__ xin, float* __restrict__ sum, float* __restrict__ sq) {
  int t = threadIdx.x;
  int c = t & 31;
  int g = t >> 5;
  float s = 0.f, q = 0.f;
  for (int r = blockIdx.x * 8 + g; r < NN; r += 2048) {
    float v = xin[r * HD + c];
    s += v;
    q += v * v;
  }
  __shared__ float ss[256], qq[256];
  ss[t] = s; qq[t] = q;
  __syncthreads();
  if (t < 128) { ss[t] += ss[t + 128]; qq[t] += qq[t + 128]; }
  __syncthreads();
  if (t < 64) { ss[t] += ss[t + 64]; qq[t] += qq[t + 64]; }
  __syncthreads();
  if (t < 32) {
    atomicAdd(&sum[c], ss[t] + ss[t + 32]);
    atomicAdd(&sq[c], qq[t] + qq[t + 32]);
  }
}

__global__ void bn_coef(const float* __restrict__ sum, const float* __restrict__ sq,
                        const void* __restrict__ g, const void* __restrict__ be,
                        const int* __restrict__ flg, float* __restrict__ a, float* __restrict__ bb) {
  int isf = *flg;
  int c = threadIdx.x;
  if (c < 32) {
    float m = sum[c] * (1.0f / 8192.0f);
    float var = fmaxf(sq[c] * (1.0f / 8192.0f) - m * m, 0.0f);
    float rstd = rsqrtf(var + EPSBN);
    float ac = ldin(g, c, isf) * rstd;
    a[c] = ac;
    bb[c] = ldin(be, c, isf) - m * ac;
  }
}

// ---------- b1 = b @ Wa0 (MFMA split-K x8, atomic f32 accumulate) ----------
__global__ void gemm_b_wa0(const void* __restrict__ Bm, const unsigned short* __restrict__ Bp,
                           const int* __restrict__ flg, float* __restrict__ b1) {
  int isf = *flg;
  int t = threadIdx.x;
  int w = (blockIdx.x << 2) + (t >> 6);
  int L = t & 63;
  int rt = w >> 3, kq = w & 7;
  int q = L >> 4, n = L & 15;
  size_t aoff = (size_t)(rt * 16 + n) * NN + kq * 1024 + q * 8;
  f32x4 acc0 = {0.f, 0.f, 0.f, 0.f};
  f32x4 acc1 = {0.f, 0.f, 0.f, 0.f};
  int kb0 = kq * 32;
  if (isf) {
    const float* arow = (const float*)Bm + aoff;
    for (int i = 0; i < 32; i++) {
      f32x4 u0 = *(const f32x4*)(arow + i * 32);
      f32x4 u1 = *(const f32x4*)(arow + i * 32 + 4);
      union { unsigned short s[8]; short8 v; } au;
      au.s[0] = f2bf(u0[0]); au.s[1] = f2bf(u0[1]); au.s[2] = f2bf(u0[2]); au.s[3] = f2bf(u0[3]);
      au.s[4] = f2bf(u1[0]); au.s[5] = f2bf(u1[1]); au.s[6] = f2bf(u1[2]); au.s[7] = f2bf(u1[3]);
      const unsigned short* bpp = Bp + (size_t)((kb0 + i) * 2) * 512 + L * 8;
      acc0 = __builtin_amdgcn_mfma_f32_16x16x32_bf16(au.v, ld_bf8(bpp), acc0, 0, 0, 0);
      acc1 = __builtin_amdgcn_mfma_f32_16x16x32_bf16(au.v, ld_bf8(bpp + 512), acc1, 0, 0, 0);
    }
  } else {
    const unsigned short* arow = (const unsigned short*)Bm + aoff;
    for (int i = 0; i < 32; i++) {
      short8 a = ld_bf8(arow + i * 32);
      const unsigned short* bpp = Bp + (size_t)((kb0 + i) * 2) * 512 + L * 8;
      acc0 = __builtin_amdgcn_mfma_f32_16x16x32_bf16(a, ld_bf8(bpp), acc0, 0, 0, 0);
      acc1 = __builtin_amdgcn_mfma_f32_16x16x32_bf16(a, ld_bf8(bpp + 512), acc1, 0, 0, 0);
    }
  }
  int orow = rt * 16 + q * 4;
  for (int r = 0; r < 4; r++) {
    atomicAdd(&b1[(orow + r) * HD + n], acc0[r]);
    atomicAdd(&b1[(orow + r) * HD + n + 16], acc1[r]);
  }
}

// ---------- x0 = relu(a0*agg0+bb0); h1in(in-place over agg0) = x0 + b1 + ba0 ----------
__global__ void fuse0(float* __restrict__ aggA, const float* __restrict__ b1,
                      const void* __restrict__ ba0, const float* __restrict__ a,
                      const float* __restrict__ bb, const int* __restrict__ flg,
                      float* __restrict__ x0) {
  int isf = *flg;
  int i = blockIdx.x * 256 + threadIdx.x;
  int c = i & 31;
  float xv = fmaxf(a[c] * aggA[i] + bb[c], 0.0f);
  x0[i] = xv;
  aggA[i] = xv + b1[i] + ldin(ba0, c, isf);
}

// ---------- h1mat = h1in @ W1 (in-place safe: rows staged to LDS first) ----------
__global__ void gemm_h_w1(float* __restrict__ hbuf, const void* __restrict__ W1,
                          const int* __restrict__ flg) {
  int isf = *flg;
  __shared__ float sW[1024], sh[256];
  int t = threadIdx.x;
  for (int i = t; i < 1024; i += 256) sW[i] = ldin(W1, i, isf);
  int row0 = blockIdx.x * 8;
  {
    int r = t >> 5, k = t & 31;
    sh[t] = hbuf[(row0 + r) * HD + k];
  }
  __syncthreads();
  int r = t >> 5, c = t & 31;
  float acc = 0.f;
  for (int k = 0; k < 32; k++) acc += sh[r * 32 + k] * sW[k * HD + c];
  hbuf[(row0 + r) * HD + c] = acc;
}

// ---------- x1 = relu(a1*agg1+bb1), in place ----------
__global__ void bn_relu(float* __restrict__ agg, const float* __restrict__ a,
                        const float* __restrict__ bb) {
  int i = blockIdx.x * 256 + threadIdx.x;
  int c = i & 31;
  agg[i] = fmaxf(a[c] * agg[i] + bb[c], 0.0f);
}

// ---------- classifier: log_softmax([x0 x1] @ Wj + bj) ----------
__global__ void classifier(const float* __restrict__ x0, const float* __restrict__ x1,
                           const void* __restrict__ Wj, const void* __restrict__ bj,
                           const int* __restrict__ flg, void* __restrict__ outv) {
  int isf = *flg;
  __shared__ float sW[64 * NC];
  __shared__ float sb[NC];
  int t = threadIdx.x;
  for (int i = t; i < 64 * NC; i += 256) sW[i] = ldin(Wj, i, isf);
  if (t < NC) sb[t] = ldin(bj, t, isf);
  __syncthreads();
  int row = blockIdx.x * 256 + t;
  float lg[NC];
  for (int c = 0; c < NC; c++) lg[c] = sb[c];
  for (int k = 0; k < 32; k++) {
    float v = x0[row * HD + k];
    for (int c = 0; c < NC; c++) lg[c] += v * sW[k * NC + c];
  }
  for (int k = 0; k < 32; k++) {
    float v = x1[row * HD + k];
    for (int c = 0; c < NC; c++) lg[c] += v * sW[(32 + k) * NC + c];
  }
  float mx = lg[0];
  for (int c = 1; c < NC; c++) mx = fmaxf(mx, lg[c]);
  float se = 0.f;
  for (int c = 0; c < NC; c++) se += expf(lg[c] - mx);
  float lse = mx + logf(se);
  if (isf) {
    float* o = (float*)outv;
    for (int c = 0; c < NC; c++) o[row * NC + c] = lg[c] - lse;
  } else {
    unsigned short* o = (unsigned short*)outv;
    for (int c = 0; c < NC; c++) o[row * NC + c] = f2bf(lg[c] - lse);
  }
}

// ---------- out1 = (b1+ba0) @ M + r2 (MFMA K=32). Reads ONLY d_ws buffers. ----------
__global__ void gemm_b4(const float* __restrict__ b1, const void* __restrict__ ba0,
                        const unsigned short* __restrict__ Rp, const float* __restrict__ r2,
                        const int* __restrict__ flg, void* __restrict__ outv) {
  int isf = *flg;
  int t = threadIdx.x;
  int w = (blockIdx.x << 2) + (t >> 6);
  int L = t & 63;
  int rt = w >> 3, jc = w & 7;
  int q = L >> 4, n = L & 15;
  const float* ap = b1 + (size_t)(rt * 16 + n) * HD + q * 8;
  union { unsigned short s[8]; short8 v; } au;
  for (int j = 0; j < 8; j++) au.s[j] = f2bf(ap[j] + ldin(ba0, q * 8 + j, isf));
  short8 afrag = au.v;
  int orow = rt * 16 + q * 4;
  float* of = (float*)outv + NN * NC;
  unsigned short* ob = (unsigned short*)outv + NN * NC;
  for (int jt = jc * 64; jt < (jc + 1) * 64; jt++) {
    short8 bfrag = ld_bf8(Rp + (size_t)(jt * 64 + L) * 8);
    f32x4 acc = {0.f, 0.f, 0.f, 0.f};
    acc = __builtin_amdgcn_mfma_f32_16x16x32_bf16(afrag, bfrag, acc, 0, 0, 0);
    int col = jt * 16 + n;
    float radd = r2[col];
    size_t base = (size_t)orow * NN + col;
    if (isf) {
      of[base] = acc[0] + radd;
      of[base + NN] = acc[1] + radd;
      of[base + 2 * NN] = acc[2] + radd;
      of[base + 3 * NN] = acc[3] + radd;
    } else {
      ob[base] = f2bf(acc[0] + radd);
      ob[base + NN] = f2bf(acc[1] + radd);
      ob[base + 2 * NN] = f2bf(acc[2] + radd);
      ob[base + 3 * NN] = f2bf(acc[3] + radd);
    }
  }
}

extern "C" void kernel_launch(void* const* d_in, const int* in_sizes, int n_in,
                              void* d_out, int out_size, void* d_ws, size_t ws_size,
                              hipStream_t stream) {
  const void* B   = d_in[0];
  const void* X   = d_in[1];
  const int* EI   = (const int*)d_in[2];
  const void* W0  = d_in[3];
  const void* W1  = d_in[5];
  const void* g0  = d_in[7];
  const void* be0 = d_in[8];
  const void* g1  = d_in[9];
  const void* be1 = d_in[10];
  const void* Wa0 = d_in[11];
  const void* ba0 = d_in[12];
  const void* Wa1 = d_in[13];
  const void* ba1 = d_in[14];
  const void* Wa2 = d_in[15];
  const void* ba2 = d_in[16];
  const void* Wa3 = d_in[17];
  const void* ba3 = d_in[18];
  const void* Wj  = d_in[19];
  const void* bj  = d_in[20];
  (void)in_sizes; (void)n_in; (void)ws_size;

  const int* esrc = EI;
  const int* edst = EI + NE;

  // ---- d_ws layout (only what gemm_b4 needs + tiny stats): ~1.6 MB total ----
  float* ws   = (float*)d_ws;
  int* flag   = (int*)ws;             // 16 floats
  float* stats = ws + 16;             // 256 (sums/sq/coefs)
  float* sum0 = stats, * sq0 = stats + 32, * sum1 = stats + 64, * sq1 = stats + 96;
  float* a0c = stats + 128, * bb0c = stats + 160, * a1c = stats + 192, * bb1c = stats + 224;
  float* b1   = stats + 256;          // NN*HD (zeroed)
  float* r2   = b1 + NN * HD;         // NN
  float* T    = r2 + NN;              // 1024
  float* vv   = T + 1024;             // 32
  unsigned short* Rp = (unsigned short*)(vv + 32);  // 512*64*8 bf16 = 512 KB
  size_t wsZeroBytes = (size_t)(16 + 256 + NN * HD) * sizeof(float);

  // ---- big scratch inside d_out's out1 region (>=134 MB, overwritten by gemm_b4 last) ----
  // Place at tail of the MINIMUM (bf16) buffer size so it is valid for either out dtype.
  size_t outBytesMin = (size_t)out_size * 2;
  size_t scratchBytes = (size_t)(NN + 3 * NN * HD) * 4 + (size_t)(256 * 2 * 64 * 8) * 2;
  char* sc = (char*)d_out + ((outBytesMin - scratchBytes) & ~(size_t)255);
  float* degv = (float*)sc;           // NN   (deg -> dinv in place, zeroed)
  float* aggA = degv + NN;            // NN*HD (agg0 -> h1in -> h1mat, zeroed)
  float* aggB = aggA + NN * HD;       // NN*HD (agg1 -> x1, zeroed)
  float* x0h  = aggB + NN * HD;       // NN*HD (h0 -> x0)
  unsigned short* Bp = (unsigned short*)(x0h + NN * HD);  // 512 KB
  size_t outZeroBytes = (size_t)(NN + 2 * NN * HD) * sizeof(float);

  hipMemsetAsync(ws, 0, wsZeroBytes, stream);
  hipMemsetAsync(degv, 0, outZeroBytes, stream);

  detect_k<<<1, 256, 0, stream>>>(B, flag);
  prep_T<<<1, 1024, 0, stream>>>(Wa1, ba1, Wa2, ba2, flag, T, vv);
  compute_Rp<<<32, 256, 0, stream>>>(Wa3, ba3, T, vv, flag, r2, Rp);
  pack_Bp<<<128, 256, 0, stream>>>(Wa0, flag, Bp);
  deg_k<<<NE / 256, 256, 0, stream>>>(edst, degv);
  dinv_k<<<NN / 256, 256, 0, stream>>>(degv);
  gemm_x_w0<<<NN / 8, 256, 0, stream>>>(X, W0, flag, x0h);      // h0
  gemm_b_wa0<<<1024, 256, 0, stream>>>(B, Bp, flag, b1);
  scatter_agg<<<(NE + NN) * HD / 256, 256, 0, stream>>>(esrc, edst, degv, x0h, aggA);
  bn_stats<<<256, 256, 0, stream>>>(aggA, sum0, sq0);
  bn_coef<<<1, 64, 0, stream>>>(sum0, sq0, g0, be0, flag, a0c, bb0c);
  fuse0<<<NN * HD / 256, 256, 0, stream>>>(aggA, b1, ba0, a0c, bb0c, flag, x0h);  // aggA<-h1in, x0h<-x0
  gemm_h_w1<<<NN / 8, 256, 0, stream>>>(aggA, W1, flag);        // aggA<-h1mat (in place)
  scatter_agg<<<(NE + NN) * HD / 256, 256, 0, stream>>>(esrc, edst, degv, aggA, aggB);
  bn_stats<<<256, 256, 0, stream>>>(aggB, sum1, sq1);
  bn_coef<<<1, 64, 0, stream>>>(sum1, sq1, g1, be1, flag, a1c, bb1c);
  bn_relu<<<NN * HD / 256, 256, 0, stream>>>(aggB, a1c, bb1c);  // aggB<-x1
  classifier<<<NN / 256, 256, 0, stream>>>(x0h, aggB, Wj, bj, flag, d_out);
  gemm_b4<<<1024, 256, 0, stream>>>(b1, ba0, Rp, r2, flag, d_out);  // overwrites all scratch in out1
}